// Round 3
// baseline (502.721 us; speedup 1.0000x reference)
//
#include <hip/hip_runtime.h>

// GKAT layer, restructured:
//   ret = elu( (S @ (C @ V_ext)) / (S @ rowsum(C) + eps) )
// where S = exp(scale*Q@K^T - M_i), M_i = ||Q_i|| * max_j ||K_j|| * scale
// (Cauchy-Schwarz upper bound on rowmax; exact rowmax cancels in the ratio).
// V_ext = [V | ones | pad] so rowsum(C) rides as column 128 of C@V_ext.
//
// R9: flash software pipeline, zero LDS cost (R8 = 501.5us).
//  - Ks(c+1) DMA issued AFTER barrier B (all QK reads of Ks provably done)
//    -> Ks L2 latency hides under the whole PV phase + next loop top.
//  - Cs(c) DMA issued right after barrier A -> hides under QK+exp.
//  - 2 barriers/chunk instead of 3; all waits are plain vmcnt(0) at points
//    where the drained loads have had a full compute phase in flight.
//  - sched_barrier(0) pins phase edges (compiler must not hoist ds_reads
//    across raw s_barrier or sink the DMA issues below the MFMA cluster).

#define SCALE 0.088388347648318447f   // 1/sqrt(128)

typedef __attribute__((ext_vector_type(8))) short bf16x8;   // 8 bf16 (4 VGPRs)
typedef __attribute__((ext_vector_type(4))) short bf16x4;   // 8-byte LDS loads
typedef __attribute__((ext_vector_type(4))) float f32x4;

static __device__ __forceinline__ unsigned short f2bf(float f) {
    unsigned u = __float_as_uint(f);
    u = (u + 0x7fffu + ((u >> 16) & 1u)) >> 16;   // RNE
    return (unsigned short)u;
}
static __device__ __forceinline__ float bf2f(unsigned short b) {
    return __uint_as_float(((unsigned)b) << 16);
}
static __device__ __forceinline__ bf16x8 pack8(const float4& a, const float4& b) {
    bf16x8 v;
    v[0] = (short)f2bf(a.x); v[1] = (short)f2bf(a.y);
    v[2] = (short)f2bf(a.z); v[3] = (short)f2bf(a.w);
    v[4] = (short)f2bf(b.x); v[5] = (short)f2bf(b.y);
    v[6] = (short)f2bf(b.z); v[7] = (short)f2bf(b.w);
    return v;
}
// async global->LDS DMA, 16B/lane; LDS dest = wave-uniform base + lane*16
static __device__ __forceinline__ void gl_lds16(const unsigned short* g, unsigned short* l) {
    __builtin_amdgcn_global_load_lds(
        (const __attribute__((address_space(1))) unsigned int*)g,
        (__attribute__((address_space(3))) unsigned int*)l, 16, 0, 0);
}

// ---------------------------------------------------------------------------
// Kernel 1: one block = 64 feat rows x one full W matrix. Single barrier.
// ---------------------------------------------------------------------------
__global__ __launch_bounds__(512) void qkv_mfma(
    const float* __restrict__ feat, const float* __restrict__ Wq,
    const float* __restrict__ Wk, const float* __restrict__ Wv,
    unsigned short* __restrict__ Qb, unsigned short* __restrict__ Kb,
    unsigned short* __restrict__ VbT) {
    __shared__ unsigned short As[64][264];
    __shared__ unsigned short Bs[128][264];
    const int tid = threadIdx.x;
    const int m0 = blockIdx.x * 64;
    const int mat = blockIdx.y;
    const float* W = (mat == 0) ? Wq : (mat == 1) ? Wk : Wv;
    const int lane = tid & 63, wv = tid >> 6;
    const int wm = wv & 3, wn = wv >> 2;
    const int ln15 = lane & 15, quad = lane >> 4;

    #pragma unroll
    for (int i = 0; i < 4; i++) {
        int s = tid + i * 512;
        int r = s >> 5, c8 = s & 31;
        const float* p = feat + (size_t)(m0 + r) * 256 + c8 * 8;
        const float4 f0 = *(const float4*)p;
        const float4 f1 = *(const float4*)(p + 4);
        *(bf16x8*)&As[r][c8 * 8] = pack8(f0, f1);
    }
    #pragma unroll
    for (int i = 0; i < 16; i++) {
        int s = tid + i * 512;
        int k = s >> 5, n4 = (s & 31) * 4;
        const float4 f = *(const float4*)(W + (size_t)k * 128 + n4);
        Bs[n4 + 0][k] = f2bf(f.x); Bs[n4 + 1][k] = f2bf(f.y);
        Bs[n4 + 2][k] = f2bf(f.z); Bs[n4 + 3][k] = f2bf(f.w);
    }
    __syncthreads();

    f32x4 acc[4];
    #pragma unroll
    for (int t = 0; t < 4; t++) acc[t] = f32x4{0.f, 0.f, 0.f, 0.f};
    #pragma unroll
    for (int ks = 0; ks < 8; ks++) {
        bf16x8 af = *(const bf16x8*)&As[wm * 16 + ln15][ks * 32 + quad * 8];
        #pragma unroll
        for (int t = 0; t < 4; t++) {
            bf16x8 bf = *(const bf16x8*)&Bs[wn * 64 + t * 16 + ln15][ks * 32 + quad * 8];
            acc[t] = __builtin_amdgcn_mfma_f32_16x16x32_bf16(af, bf, acc[t], 0, 0, 0);
        }
    }
    #pragma unroll
    for (int t = 0; t < 4; t++) {
        int n = wn * 64 + t * 16 + ln15;
        int mb = m0 + wm * 16 + quad * 4;
        if (mat == 2) {
            ushort4 w;
            w.x = f2bf(acc[t][0]); w.y = f2bf(acc[t][1]);
            w.z = f2bf(acc[t][2]); w.w = f2bf(acc[t][3]);
            *(ushort4*)(VbT + (size_t)n * 8192 + mb) = w;
        } else {
            unsigned short* dst = (mat == 0) ? Qb : Kb;
            #pragma unroll
            for (int reg = 0; reg < 4; reg++)
                dst[(size_t)(mb + reg) * 128 + n] = f2bf(acc[t][reg]);
        }
    }
    if (mat == 2) {
        #pragma unroll
        for (int i = 0; i < 8; i++) {
            int idx = tid + i * 512;
            int rr = idx >> 6, c = idx & 63;
            VbT[(size_t)(128 + rr) * 8192 + m0 + c] =
                (rr == 0) ? (unsigned short)0x3F80 : (unsigned short)0;
        }
    }
}

// ---------------------------------------------------------------------------
// Kernel 2: row norms of Q, global max row-norm^2 of K.
// 256 blocks x 256 thr, 32 rows/block, ONE atomicMax per block.
// ---------------------------------------------------------------------------
__global__ __launch_bounds__(256) void norms_kernel(
    const unsigned short* __restrict__ Qb, const unsigned short* __restrict__ Kb,
    float* __restrict__ qn2, unsigned* __restrict__ knmax) {
    const int tid = threadIdx.x;
    const int lane = tid & 63, wv = tid >> 6;
    const int r0 = blockIdx.x * 32;
    float kmax = 0.f;
    #pragma unroll
    for (int it = 0; it < 8; it++) {
        int r = r0 + it * 4 + wv;
        const unsigned short* qp = Qb + (size_t)r * 128;
        const unsigned short* kp = Kb + (size_t)r * 128;
        ushort2 qv = *(const ushort2*)(qp + lane * 2);
        ushort2 kv = *(const ushort2*)(kp + lane * 2);
        float q0 = bf2f(qv.x), q1 = bf2f(qv.y);
        float k0 = bf2f(kv.x), k1 = bf2f(kv.y);
        float sq = q0 * q0 + q1 * q1;
        float sk = k0 * k0 + k1 * k1;
        #pragma unroll
        for (int m = 1; m < 64; m <<= 1) {
            sq += __shfl_xor(sq, m, 64);
            sk += __shfl_xor(sk, m, 64);
        }
        if (lane == 0) qn2[r] = sq;
        kmax = fmaxf(kmax, sk);
    }
    __shared__ float sm[4];
    if (lane == 0) sm[wv] = kmax;
    __syncthreads();
    if (tid == 0) {
        float m = fmaxf(fmaxf(sm[0], sm[1]), fmaxf(sm[2], sm[3]));
        atomicMax(knmax, __float_as_uint(m));
    }
}

// ---------------------------------------------------------------------------
// Kernel 3: CVpart[sp] = C[m-range][k-range] @ V_ext^T.  M=64/block,
// ksplit 8 -> grid 1024 (4 blocks/CU).  A read fp32 directly (dist-1 reg
// prefetch, each C element read once), B via 16B DMA.  XOR-swizzled tiles.
// Counted vmcnt(4): the 4 next-chunk A prefetch loads ride through MFMA.
// ---------------------------------------------------------------------------
__global__ __launch_bounds__(256, 4) void cv_kernel(
    const float* __restrict__ C, const unsigned short* __restrict__ VbT,
    float* __restrict__ CVpart) {
    __shared__ unsigned short As[64 * 64];    // 8 KB, swizzled
    __shared__ unsigned short Bs[192 * 64];   // 24 KB, swizzled
    const int tid = threadIdx.x;
    const int rg = blockIdx.x >> 3, sp = blockIdx.x & 7;
    const int m0 = rg * 64;
    const int k0 = sp * 1024;                 // 16 chunks of 64
    const int lane = tid & 63, wv = tid >> 6;
    const int mh = wv & 1, h2 = wv >> 1;
    const int ln15 = lane & 15, quad = lane >> 4;

    const int r0 = tid >> 3, gc = tid & 7;    // A slots: (r0, gc) and (r0+32, gc)
    const int gsw = gc ^ (r0 & 7);            // (r0+32)&7 == r0&7
    const float* A0 = C + (size_t)(m0 + r0) * 8192 + k0 + gc * 8;
    const float* A1 = A0 + (size_t)32 * 8192;

    float4 pa[4];
    pa[0] = *(const float4*)A0; pa[1] = *(const float4*)(A0 + 4);
    pa[2] = *(const float4*)A1; pa[3] = *(const float4*)(A1 + 4);

    f32x4 acc[2][5];
    #pragma unroll
    for (int mt = 0; mt < 2; mt++)
        #pragma unroll
        for (int t = 0; t < 5; t++) acc[mt][t] = f32x4{0.f, 0.f, 0.f, 0.f};

    const int ra0 = mh * 32 + ln15;
    const int ra1 = mh * 32 + 16 + ln15;

    for (int c = 0; c < 16; c++) {
        __syncthreads();   // prev chunk's LDS reads done; prefetch regs drained
        *(bf16x8*)&As[r0 * 64 + gsw * 8]        = pack8(pa[0], pa[1]);
        *(bf16x8*)&As[(r0 + 32) * 64 + gsw * 8] = pack8(pa[2], pa[3]);
        // B DMA: 192 rows x 8 groups = 1536 slots, 6 wave-instrs
        #pragma unroll
        for (int i = 0; i < 6; i++) {
            int s = (i * 4 + wv) * 64 + lane;
            int r = s >> 3, g = (s & 7) ^ (r & 7);
            gl_lds16(VbT + (size_t)r * 8192 + k0 + c * 64 + g * 8,
                     &Bs[(i * 4 + wv) * 512]);
        }
        // compiler memory fence: prefetch loads must ISSUE after the 6 DMAs
        // so the counted vmcnt below refers to the DMAs.
        asm volatile("" ::: "memory");
        if (c + 1 < 16) {   // dist-1 prefetch of next A chunk (fp32)
            const float* p0 = A0 + (c + 1) * 64;
            const float* p1 = A1 + (c + 1) * 64;
            pa[0] = *(const float4*)p0; pa[1] = *(const float4*)(p0 + 4);
            pa[2] = *(const float4*)p1; pa[3] = *(const float4*)(p1 + 4);
            // 6 DMA + 4 prefetch outstanding; wait DMAs only (oldest 6)
            asm volatile("s_waitcnt vmcnt(4) lgkmcnt(0)" ::: "memory");
        } else {
            asm volatile("s_waitcnt vmcnt(0) lgkmcnt(0)" ::: "memory");
        }
        __builtin_amdgcn_s_barrier();
        __builtin_amdgcn_sched_barrier(0);
        #pragma unroll
        for (int k2 = 0; k2 < 2; k2++) {
            const int lg = k2 * 4 + quad;
            bf16x8 a0 = *(const bf16x8*)&As[ra0 * 64 + ((lg ^ (ra0 & 7)) * 8)];
            bf16x8 a1 = *(const bf16x8*)&As[ra1 * 64 + ((lg ^ (ra1 & 7)) * 8)];
            #pragma unroll
            for (int t = 0; t < 5; t++) {
                int n = h2 * 80 + t * 16 + ln15;
                bf16x8 bf = *(const bf16x8*)&Bs[n * 64 + ((lg ^ (n & 7)) * 8)];
                acc[0][t] = __builtin_amdgcn_mfma_f32_16x16x32_bf16(a0, bf, acc[0][t], 0, 0, 0);
                acc[1][t] = __builtin_amdgcn_mfma_f32_16x16x32_bf16(a1, bf, acc[1][t], 0, 0, 0);
            }
        }
    }
    float* dst = CVpart + (size_t)sp * 160 * 8192;
    #pragma unroll
    for (int mt = 0; mt < 2; mt++)
        #pragma unroll
        for (int t = 0; t < 5; t++) {
            int n = h2 * 80 + t * 16 + ln15;
            int m = m0 + mh * 32 + mt * 16 + quad * 4;
            float4 w;
            w.x = acc[mt][t][0]; w.y = acc[mt][t][1];
            w.z = acc[mt][t][2]; w.w = acc[mt][t][3];
            *(float4*)(dst + (size_t)n * 8192 + m) = w;
        }
}

// ---------------------------------------------------------------------------
// Kernel 3b: CVbT bf16 = sum of 8 partials.
// ---------------------------------------------------------------------------
__global__ __launch_bounds__(256) void cvreduce_kernel(
    const float* __restrict__ CVpart, unsigned short* __restrict__ CVbT) {
    const size_t STR = (size_t)160 * 8192;
    int idx = blockIdx.x * 256 + threadIdx.x;    // 327680 float4-slots
    const float* p = CVpart + (size_t)idx * 4;
    float4 s = *(const float4*)p;
    #pragma unroll
    for (int j = 1; j < 8; j++) {
        const float4 q = *(const float4*)(p + j * STR);
        s.x += q.x; s.y += q.y; s.z += q.z; s.w += q.w;
    }
    ushort4 w;
    w.x = f2bf(s.x); w.y = f2bf(s.y); w.z = f2bf(s.z); w.w = f2bf(s.w);
    *(ushort4*)(CVbT + (size_t)idx * 4) = w;
}

// ---------------------------------------------------------------------------
// Kernel 4 v8 (R9): 2-barrier software-pipelined chunk loop.
// Per chunk c:
//   wait vmcnt(0)+lgkm; barrier A            // Ks(c) (issued during PV(c-1))
//   issue Cs(c) DMA                          // hides under QK+exp
//   QK(c); exp -> Ps
//   wait vmcnt(0)+lgkm; barrier B            // Cs(c)+Ps visible; Ks reads done
//   issue Ks(c+1) DMA                        // hides under PV(c)
//   PV(c)
// Single-buffered Ks/Cs stay safe because each is overwritten only after the
// barrier proving its readers are done (B for Ks, A for Cs).
// ---------------------------------------------------------------------------
__global__ __launch_bounds__(256, 3) void flash_kernel(
    const unsigned short* __restrict__ Qb, const unsigned short* __restrict__ Kb,
    const unsigned short* __restrict__ CVbT, const float* __restrict__ qn2,
    const unsigned* __restrict__ knmax, float* __restrict__ Opart) {
    __shared__ unsigned short Ks[64 * 128];   // 16 KB, 16-group swizzle
    __shared__ unsigned short Cs[160 * 64];   // 20 KB, 8-group swizzle
    __shared__ unsigned short Ps[64][68];     // 8.5 KB
    const int tid = threadIdx.x;
    const int rg = blockIdx.x >> 3, sp = blockIdx.x & 7;
    const int i0 = rg * 64;
    const int k0 = sp * 1024;                 // 16 chunks of 64 keys
    const int lane = tid & 63, wv = tid >> 6;
    const int ln15 = lane & 15, quad = lane >> 4;
    const int p2 = wv & 1;    // m-half: rows 32*p2..+32
    const int h2 = wv >> 1;   // QK: key-half; PV: n-half

    // Q A-fragments in registers (wave only needs its own 32 rows)
    bf16x8 qf[2][4];
    #pragma unroll
    for (int mt = 0; mt < 2; mt++)
        #pragma unroll
        for (int kk = 0; kk < 4; kk++) {
            int row = i0 + p2 * 32 + mt * 16 + ln15;
            qf[mt][kk] = *(const bf16x8*)(Qb + (size_t)row * 128 + kk * 32 + quad * 8);
        }
    const float kn2 = __uint_as_float(*knmax);
    float Msr[2][4];
    #pragma unroll
    for (int mt = 0; mt < 2; mt++)
        #pragma unroll
        for (int reg = 0; reg < 4; reg++) {
            int row = p2 * 32 + mt * 16 + quad * 4 + reg;
            Msr[mt][reg] = sqrtf(qn2[i0 + row] * kn2) * SCALE;
        }

    f32x4 acc[2][5];
    #pragma unroll
    for (int mt = 0; mt < 2; mt++)
        #pragma unroll
        for (int t = 0; t < 5; t++) acc[mt][t] = f32x4{0.f, 0.f, 0.f, 0.f};

    // prologue: issue Ks(0)
    #pragma unroll
    for (int i = 0; i < 4; i++) {
        int s = (i * 4 + wv) * 64 + lane;
        int r = s >> 4, g = (s & 15) ^ (r & 15);
        gl_lds16(Kb + (size_t)(k0 + r) * 128 + g * 8, &Ks[(i * 4 + wv) * 512]);
    }

    for (int c = 0; c < 16; c++) {
        const int kb = k0 + c * 64;
        // ---- barrier A: Ks(c) visible; PV(c-1) LDS reads done ----
        asm volatile("s_waitcnt vmcnt(0) lgkmcnt(0)" ::: "memory");
        __builtin_amdgcn_s_barrier();
        __builtin_amdgcn_sched_barrier(0);

        // Cs(c) DMA: 160 rows x 8 groups = 1280 slots, 5 wave-instrs
        // (safe: barrier A proved PV(c-1)'s Cs reads complete)
        #pragma unroll
        for (int i = 0; i < 5; i++) {
            int s = (i * 4 + wv) * 64 + lane;
            int r = s >> 3, g = (s & 7) ^ (r & 7);
            gl_lds16(CVbT + (size_t)r * 8192 + kb + g * 8, &Cs[(i * 4 + wv) * 512]);
        }
        __builtin_amdgcn_sched_barrier(0);   // pin DMA issue before QK

        // QK: rows 32*p2..+32 x keys 32*h2..+32
        f32x4 pacc[2][2];
        #pragma unroll
        for (int mt = 0; mt < 2; mt++)
            #pragma unroll
            for (int kt = 0; kt < 2; kt++) pacc[mt][kt] = f32x4{0.f, 0.f, 0.f, 0.f};
        #pragma unroll
        for (int kk = 0; kk < 4; kk++) {
            #pragma unroll
            for (int kt = 0; kt < 2; kt++) {
                int r = h2 * 32 + kt * 16 + ln15;
                int lg = kk * 4 + quad;
                bf16x8 bk = *(const bf16x8*)&Ks[r * 128 + ((lg ^ (r & 15)) * 8)];
                pacc[0][kt] = __builtin_amdgcn_mfma_f32_16x16x32_bf16(qf[0][kk], bk, pacc[0][kt], 0, 0, 0);
                pacc[1][kt] = __builtin_amdgcn_mfma_f32_16x16x32_bf16(qf[1][kk], bk, pacc[1][kt], 0, 0, 0);
            }
        }
        #pragma unroll
        for (int mt = 0; mt < 2; mt++)
            #pragma unroll
            for (int kt = 0; kt < 2; kt++)
                #pragma unroll
                for (int reg = 0; reg < 4; reg++) {
                    int row = p2 * 32 + mt * 16 + quad * 4 + reg;
                    int key = h2 * 32 + kt * 16 + ln15;
                    float p = __expf(pacc[mt][kt][reg] * SCALE - Msr[mt][reg]);
                    Ps[row][key] = f2bf(p);
                }

        // ---- barrier B: Cs(c) + Ps visible; Ks(c) reads done block-wide ----
        asm volatile("s_waitcnt vmcnt(0) lgkmcnt(0)" ::: "memory");
        __builtin_amdgcn_s_barrier();
        __builtin_amdgcn_sched_barrier(0);

        // Ks(c+1) DMA (safe: barrier B proved all QK reads of Ks done);
        // rides through the whole PV phase + next loop top.
        if (c + 1 < 16) {
            const int kb2 = k0 + (c + 1) * 64;
            #pragma unroll
            for (int i = 0; i < 4; i++) {
                int s = (i * 4 + wv) * 64 + lane;
                int r = s >> 4, g = (s & 15) ^ (r & 15);
                gl_lds16(Kb + (size_t)(kb2 + r) * 128 + g * 8, &Ks[(i * 4 + wv) * 512]);
            }
        }
        __builtin_amdgcn_sched_barrier(0);   // pin DMA issue before PV

        // PV: rows 32*p2..+32 x n = 80*h2..+80
        #pragma unroll
        for (int ks = 0; ks < 2; ks++) {
            bf16x4 lo0 = *(const bf16x4*)&Ps[p2 * 32 + ln15][ks * 32 + quad * 8];
            bf16x4 hi0 = *(const bf16x4*)&Ps[p2 * 32 + ln15][ks * 32 + quad * 8 + 4];
            bf16x4 lo1 = *(const bf16x4*)&Ps[p2 * 32 + 16 + ln15][ks * 32 + quad * 8];
            bf16x4 hi1 = *(const bf16x4*)&Ps[p2 * 32 + 16 + ln15][ks * 32 + quad * 8 + 4];
            bf16x8 ap0, ap1;
            #pragma unroll
            for (int j = 0; j < 4; j++) {
                ap0[j] = lo0[j]; ap0[j + 4] = hi0[j];
                ap1[j] = lo1[j]; ap1[j + 4] = hi1[j];
            }
            #pragma unroll
            for (int t = 0; t < 5; t++) {
                int n = h2 * 80 + t * 16 + ln15;
                int lg = ks * 4 + quad;
                bf16x8 bc = *(const bf16x8*)&Cs[n * 64 + ((lg ^ (n & 7)) * 8)];
                acc[0][t] = __builtin_amdgcn_mfma_f32_16x16x32_bf16(ap0, bc, acc[0][t], 0, 0, 0);
                acc[1][t] = __builtin_amdgcn_mfma_f32_16x16x32_bf16(ap1, bc, acc[1][t], 0, 0, 0);
            }
        }
    }
    // epilogue: plain stores into this split's disjoint partial buffer
    float* dst = Opart + (size_t)sp * 8192 * 160;
    #pragma unroll
    for (int mt = 0; mt < 2; mt++)
        #pragma unroll
        for (int t = 0; t < 5; t++)
            #pragma unroll
            for (int reg = 0; reg < 4; reg++) {
                int row = i0 + p2 * 32 + mt * 16 + quad * 4 + reg;
                int n = h2 * 80 + t * 16 + ln15;
                dst[(size_t)row * 160 + n] = acc[mt][t][reg];
            }
}

// ---------------------------------------------------------------------------
// Kernel 5: out = elu( (sum_sp O[sp]) / (sum_sp deno[sp] + 1e-9) ).
// ---------------------------------------------------------------------------
__global__ __launch_bounds__(256) void finalize_kernel(
    const float* __restrict__ Opart, float* __restrict__ out) {
    const size_t STR = (size_t)8192 * 160;
    int idx = blockIdx.x * 256 + threadIdx.x;
    int i = idx >> 7, n = idx & 127;
    const float* p = Opart + (size_t)i * 160;
    float val = 0.f, deno = 0.f;
    #pragma unroll
    for (int sp = 0; sp < 8; sp++) {
        val  += p[sp * STR + n];
        deno += p[sp * STR + 128];
    }
    float v = val / (deno + 1e-9f);
    out[idx] = (v > 0.f) ? v : expm1f(v);
}

// ---------------------------------------------------------------------------
extern "C" void kernel_launch(void* const* d_in, const int* in_sizes, int n_in,
                              void* d_out, int out_size, void* d_ws, size_t ws_size,
                              hipStream_t stream) {
    const float* feat = (const float*)d_in[0];
    // d_in[1] = bg (unused scalar)
    const float* C    = (const float*)d_in[2];
    const float* Wq   = (const float*)d_in[3];
    const float* Wk   = (const float*)d_in[4];
    const float* Wv   = (const float*)d_in[5];
    float* out = (float*)d_out;

    char* ws = (char*)d_ws;
    unsigned short* Qb    = (unsigned short*)(ws + 0);          // 2 MB
    unsigned short* Kb    = (unsigned short*)(ws + 2097152);    // 2 MB
    unsigned short* VbT   = (unsigned short*)(ws + 4194304);    // 192x8192x2 = 3 MB
    float*          CVpart= (float*)(ws + 7340032);             // 8x160x8192x4 = 40 MB
    unsigned short* CVbT  = (unsigned short*)(ws + 49283072);   // 160x8192x2 = 2.5 MB
    float*          Opart = (float*)(ws + 51904512);            // 8x8192x160x4 = 40 MB
    float*          qn2   = (float*)(ws + 93847552);            // 32 KB
    unsigned*       knmax = (unsigned*)(ws + 93880320);         // 4 B  (~90 MB total)

    hipMemsetAsync(knmax, 0, 4, stream);
    qkv_mfma<<<dim3(128, 3), 512, 0, stream>>>(feat, Wq, Wk, Wv, Qb, Kb, VbT);
    norms_kernel<<<256, 256, 0, stream>>>(Qb, Kb, qn2, knmax);
    cv_kernel<<<1024, 256, 0, stream>>>(C, VbT, CVpart);
    cvreduce_kernel<<<1280, 256, 0, stream>>>(CVpart, CVbT);
    flash_kernel<<<1024, 256, 0, stream>>>(Qb, Kb, CVbT, qn2, knmax, Opart);
    finalize_kernel<<<4096, 256, 0, stream>>>(Opart, out);
}

// Round 4
// 488.542 us; speedup vs baseline: 1.0290x; 1.0290x over previous
//
#include <hip/hip_runtime.h>

// GKAT layer, restructured:
//   ret = elu( (S @ (C @ V_ext)) / (S @ rowsum(C) + eps) )
// where S = exp(scale*Q@K^T - M_i), M_i = ||Q_i|| * max_j ||K_j|| * scale
// (Cauchy-Schwarz upper bound on rowmax; exact rowmax cancels in the ratio).
// V_ext = [V | ones | pad] so rowsum(C) rides as column 128 of C@V_ext.
//
// R10: flash grid/occupancy balance (R9 pipeline restructure was NULL ->
// flash is throughput/occupancy-bound, not latency-bound).
//  - flash LDS = 44.5 KB -> only 3 blocks/CU co-resident, but grid was
//    1024 = 4/CU of work: a 256-block straggler shift ran at 1 block/CU
//    (1 wave/SIMD, no latency hiding) costing ~as much as the main shift.
//  - Fix: ksplit 8 -> 4, M=64: grid 512 = exactly 2 blocks/CU, single
//    balanced shift. Per-block chunks 16 -> 32. launch_bounds(256,2).
//  - Opart 40 -> 21 MB (finalize sums 4 partials).

#define SCALE 0.088388347648318447f   // 1/sqrt(128)

typedef __attribute__((ext_vector_type(8))) short bf16x8;   // 8 bf16 (4 VGPRs)
typedef __attribute__((ext_vector_type(4))) short bf16x4;   // 8-byte LDS loads
typedef __attribute__((ext_vector_type(4))) float f32x4;

static __device__ __forceinline__ unsigned short f2bf(float f) {
    unsigned u = __float_as_uint(f);
    u = (u + 0x7fffu + ((u >> 16) & 1u)) >> 16;   // RNE
    return (unsigned short)u;
}
static __device__ __forceinline__ float bf2f(unsigned short b) {
    return __uint_as_float(((unsigned)b) << 16);
}
static __device__ __forceinline__ bf16x8 pack8(const float4& a, const float4& b) {
    bf16x8 v;
    v[0] = (short)f2bf(a.x); v[1] = (short)f2bf(a.y);
    v[2] = (short)f2bf(a.z); v[3] = (short)f2bf(a.w);
    v[4] = (short)f2bf(b.x); v[5] = (short)f2bf(b.y);
    v[6] = (short)f2bf(b.z); v[7] = (short)f2bf(b.w);
    return v;
}
// async global->LDS DMA, 16B/lane; LDS dest = wave-uniform base + lane*16
static __device__ __forceinline__ void gl_lds16(const unsigned short* g, unsigned short* l) {
    __builtin_amdgcn_global_load_lds(
        (const __attribute__((address_space(1))) unsigned int*)g,
        (__attribute__((address_space(3))) unsigned int*)l, 16, 0, 0);
}

// ---------------------------------------------------------------------------
// Kernel 1: one block = 64 feat rows x one full W matrix. Single barrier.
// ---------------------------------------------------------------------------
__global__ __launch_bounds__(512) void qkv_mfma(
    const float* __restrict__ feat, const float* __restrict__ Wq,
    const float* __restrict__ Wk, const float* __restrict__ Wv,
    unsigned short* __restrict__ Qb, unsigned short* __restrict__ Kb,
    unsigned short* __restrict__ VbT) {
    __shared__ unsigned short As[64][264];
    __shared__ unsigned short Bs[128][264];
    const int tid = threadIdx.x;
    const int m0 = blockIdx.x * 64;
    const int mat = blockIdx.y;
    const float* W = (mat == 0) ? Wq : (mat == 1) ? Wk : Wv;
    const int lane = tid & 63, wv = tid >> 6;
    const int wm = wv & 3, wn = wv >> 2;
    const int ln15 = lane & 15, quad = lane >> 4;

    #pragma unroll
    for (int i = 0; i < 4; i++) {
        int s = tid + i * 512;
        int r = s >> 5, c8 = s & 31;
        const float* p = feat + (size_t)(m0 + r) * 256 + c8 * 8;
        const float4 f0 = *(const float4*)p;
        const float4 f1 = *(const float4*)(p + 4);
        *(bf16x8*)&As[r][c8 * 8] = pack8(f0, f1);
    }
    #pragma unroll
    for (int i = 0; i < 16; i++) {
        int s = tid + i * 512;
        int k = s >> 5, n4 = (s & 31) * 4;
        const float4 f = *(const float4*)(W + (size_t)k * 128 + n4);
        Bs[n4 + 0][k] = f2bf(f.x); Bs[n4 + 1][k] = f2bf(f.y);
        Bs[n4 + 2][k] = f2bf(f.z); Bs[n4 + 3][k] = f2bf(f.w);
    }
    __syncthreads();

    f32x4 acc[4];
    #pragma unroll
    for (int t = 0; t < 4; t++) acc[t] = f32x4{0.f, 0.f, 0.f, 0.f};
    #pragma unroll
    for (int ks = 0; ks < 8; ks++) {
        bf16x8 af = *(const bf16x8*)&As[wm * 16 + ln15][ks * 32 + quad * 8];
        #pragma unroll
        for (int t = 0; t < 4; t++) {
            bf16x8 bf = *(const bf16x8*)&Bs[wn * 64 + t * 16 + ln15][ks * 32 + quad * 8];
            acc[t] = __builtin_amdgcn_mfma_f32_16x16x32_bf16(af, bf, acc[t], 0, 0, 0);
        }
    }
    #pragma unroll
    for (int t = 0; t < 4; t++) {
        int n = wn * 64 + t * 16 + ln15;
        int mb = m0 + wm * 16 + quad * 4;
        if (mat == 2) {
            ushort4 w;
            w.x = f2bf(acc[t][0]); w.y = f2bf(acc[t][1]);
            w.z = f2bf(acc[t][2]); w.w = f2bf(acc[t][3]);
            *(ushort4*)(VbT + (size_t)n * 8192 + mb) = w;
        } else {
            unsigned short* dst = (mat == 0) ? Qb : Kb;
            #pragma unroll
            for (int reg = 0; reg < 4; reg++)
                dst[(size_t)(mb + reg) * 128 + n] = f2bf(acc[t][reg]);
        }
    }
    if (mat == 2) {
        #pragma unroll
        for (int i = 0; i < 8; i++) {
            int idx = tid + i * 512;
            int rr = idx >> 6, c = idx & 63;
            VbT[(size_t)(128 + rr) * 8192 + m0 + c] =
                (rr == 0) ? (unsigned short)0x3F80 : (unsigned short)0;
        }
    }
}

// ---------------------------------------------------------------------------
// Kernel 2: row norms of Q, global max row-norm^2 of K.
// 256 blocks x 256 thr, 32 rows/block, ONE atomicMax per block.
// ---------------------------------------------------------------------------
__global__ __launch_bounds__(256) void norms_kernel(
    const unsigned short* __restrict__ Qb, const unsigned short* __restrict__ Kb,
    float* __restrict__ qn2, unsigned* __restrict__ knmax) {
    const int tid = threadIdx.x;
    const int lane = tid & 63, wv = tid >> 6;
    const int r0 = blockIdx.x * 32;
    float kmax = 0.f;
    #pragma unroll
    for (int it = 0; it < 8; it++) {
        int r = r0 + it * 4 + wv;
        const unsigned short* qp = Qb + (size_t)r * 128;
        const unsigned short* kp = Kb + (size_t)r * 128;
        ushort2 qv = *(const ushort2*)(qp + lane * 2);
        ushort2 kv = *(const ushort2*)(kp + lane * 2);
        float q0 = bf2f(qv.x), q1 = bf2f(qv.y);
        float k0 = bf2f(kv.x), k1 = bf2f(kv.y);
        float sq = q0 * q0 + q1 * q1;
        float sk = k0 * k0 + k1 * k1;
        #pragma unroll
        for (int m = 1; m < 64; m <<= 1) {
            sq += __shfl_xor(sq, m, 64);
            sk += __shfl_xor(sk, m, 64);
        }
        if (lane == 0) qn2[r] = sq;
        kmax = fmaxf(kmax, sk);
    }
    __shared__ float sm[4];
    if (lane == 0) sm[wv] = kmax;
    __syncthreads();
    if (tid == 0) {
        float m = fmaxf(fmaxf(sm[0], sm[1]), fmaxf(sm[2], sm[3]));
        atomicMax(knmax, __float_as_uint(m));
    }
}

// ---------------------------------------------------------------------------
// Kernel 3: CVpart[sp] = C[m-range][k-range] @ V_ext^T.  M=64/block,
// ksplit 8 -> grid 1024 (4 blocks/CU, balanced: 32 KB LDS allows 5).
// A read fp32 directly (dist-1 reg prefetch), B via 16B DMA.  XOR-swizzled.
// Counted vmcnt(4): the 4 next-chunk A prefetch loads ride through MFMA.
// ---------------------------------------------------------------------------
__global__ __launch_bounds__(256, 4) void cv_kernel(
    const float* __restrict__ C, const unsigned short* __restrict__ VbT,
    float* __restrict__ CVpart) {
    __shared__ unsigned short As[64 * 64];    // 8 KB, swizzled
    __shared__ unsigned short Bs[192 * 64];   // 24 KB, swizzled
    const int tid = threadIdx.x;
    const int rg = blockIdx.x >> 3, sp = blockIdx.x & 7;
    const int m0 = rg * 64;
    const int k0 = sp * 1024;                 // 16 chunks of 64
    const int lane = tid & 63, wv = tid >> 6;
    const int mh = wv & 1, h2 = wv >> 1;
    const int ln15 = lane & 15, quad = lane >> 4;

    const int r0 = tid >> 3, gc = tid & 7;    // A slots: (r0, gc) and (r0+32, gc)
    const int gsw = gc ^ (r0 & 7);            // (r0+32)&7 == r0&7
    const float* A0 = C + (size_t)(m0 + r0) * 8192 + k0 + gc * 8;
    const float* A1 = A0 + (size_t)32 * 8192;

    float4 pa[4];
    pa[0] = *(const float4*)A0; pa[1] = *(const float4*)(A0 + 4);
    pa[2] = *(const float4*)A1; pa[3] = *(const float4*)(A1 + 4);

    f32x4 acc[2][5];
    #pragma unroll
    for (int mt = 0; mt < 2; mt++)
        #pragma unroll
        for (int t = 0; t < 5; t++) acc[mt][t] = f32x4{0.f, 0.f, 0.f, 0.f};

    const int ra0 = mh * 32 + ln15;
    const int ra1 = mh * 32 + 16 + ln15;

    for (int c = 0; c < 16; c++) {
        __syncthreads();   // prev chunk's LDS reads done; prefetch regs drained
        *(bf16x8*)&As[r0 * 64 + gsw * 8]        = pack8(pa[0], pa[1]);
        *(bf16x8*)&As[(r0 + 32) * 64 + gsw * 8] = pack8(pa[2], pa[3]);
        // B DMA: 192 rows x 8 groups = 1536 slots, 6 wave-instrs
        #pragma unroll
        for (int i = 0; i < 6; i++) {
            int s = (i * 4 + wv) * 64 + lane;
            int r = s >> 3, g = (s & 7) ^ (r & 7);
            gl_lds16(VbT + (size_t)r * 8192 + k0 + c * 64 + g * 8,
                     &Bs[(i * 4 + wv) * 512]);
        }
        // compiler memory fence: prefetch loads must ISSUE after the 6 DMAs
        // so the counted vmcnt below refers to the DMAs.
        asm volatile("" ::: "memory");
        if (c + 1 < 16) {   // dist-1 prefetch of next A chunk (fp32)
            const float* p0 = A0 + (c + 1) * 64;
            const float* p1 = A1 + (c + 1) * 64;
            pa[0] = *(const float4*)p0; pa[1] = *(const float4*)(p0 + 4);
            pa[2] = *(const float4*)p1; pa[3] = *(const float4*)(p1 + 4);
            // 6 DMA + 4 prefetch outstanding; wait DMAs only (oldest 6)
            asm volatile("s_waitcnt vmcnt(4) lgkmcnt(0)" ::: "memory");
        } else {
            asm volatile("s_waitcnt vmcnt(0) lgkmcnt(0)" ::: "memory");
        }
        __builtin_amdgcn_s_barrier();
        __builtin_amdgcn_sched_barrier(0);
        #pragma unroll
        for (int k2 = 0; k2 < 2; k2++) {
            const int lg = k2 * 4 + quad;
            bf16x8 a0 = *(const bf16x8*)&As[ra0 * 64 + ((lg ^ (ra0 & 7)) * 8)];
            bf16x8 a1 = *(const bf16x8*)&As[ra1 * 64 + ((lg ^ (ra1 & 7)) * 8)];
            #pragma unroll
            for (int t = 0; t < 5; t++) {
                int n = h2 * 80 + t * 16 + ln15;
                bf16x8 bf = *(const bf16x8*)&Bs[n * 64 + ((lg ^ (n & 7)) * 8)];
                acc[0][t] = __builtin_amdgcn_mfma_f32_16x16x32_bf16(a0, bf, acc[0][t], 0, 0, 0);
                acc[1][t] = __builtin_amdgcn_mfma_f32_16x16x32_bf16(a1, bf, acc[1][t], 0, 0, 0);
            }
        }
    }
    float* dst = CVpart + (size_t)sp * 160 * 8192;
    #pragma unroll
    for (int mt = 0; mt < 2; mt++)
        #pragma unroll
        for (int t = 0; t < 5; t++) {
            int n = h2 * 80 + t * 16 + ln15;
            int m = m0 + mh * 32 + mt * 16 + quad * 4;
            float4 w;
            w.x = acc[mt][t][0]; w.y = acc[mt][t][1];
            w.z = acc[mt][t][2]; w.w = acc[mt][t][3];
            *(float4*)(dst + (size_t)n * 8192 + m) = w;
        }
}

// ---------------------------------------------------------------------------
// Kernel 3b: CVbT bf16 = sum of 8 partials.
// ---------------------------------------------------------------------------
__global__ __launch_bounds__(256) void cvreduce_kernel(
    const float* __restrict__ CVpart, unsigned short* __restrict__ CVbT) {
    const size_t STR = (size_t)160 * 8192;
    int idx = blockIdx.x * 256 + threadIdx.x;    // 327680 float4-slots
    const float* p = CVpart + (size_t)idx * 4;
    float4 s = *(const float4*)p;
    #pragma unroll
    for (int j = 1; j < 8; j++) {
        const float4 q = *(const float4*)(p + j * STR);
        s.x += q.x; s.y += q.y; s.z += q.z; s.w += q.w;
    }
    ushort4 w;
    w.x = f2bf(s.x); w.y = f2bf(s.y); w.z = f2bf(s.z); w.w = f2bf(s.w);
    *(ushort4*)(CVbT + (size_t)idx * 4) = w;
}

// ---------------------------------------------------------------------------
// Kernel 4 v9 (R10): ksplit 4, M=64 -> grid 512 = exactly 2 blocks/CU,
// single balanced shift (was 1024 blocks at 3/CU residency -> 256-block
// straggler shift at 1/CU). 32 chunks/block. 2-barrier pipelined loop:
//   barrier A (Ks(c) ready) -> issue Cs(c) -> QK+exp ->
//   barrier B (Cs+Ps ready) -> issue Ks(c+1) -> PV
// ---------------------------------------------------------------------------
__global__ __launch_bounds__(256, 2) void flash_kernel(
    const unsigned short* __restrict__ Qb, const unsigned short* __restrict__ Kb,
    const unsigned short* __restrict__ CVbT, const float* __restrict__ qn2,
    const unsigned* __restrict__ knmax, float* __restrict__ Opart) {
    __shared__ unsigned short Ks[64 * 128];   // 16 KB, 16-group swizzle
    __shared__ unsigned short Cs[160 * 64];   // 20 KB, 8-group swizzle
    __shared__ unsigned short Ps[64][68];     // 8.5 KB
    const int tid = threadIdx.x;
    const int rg = blockIdx.x >> 2, sp = blockIdx.x & 3;
    const int i0 = rg * 64;
    const int k0 = sp * 2048;                 // 32 chunks of 64 keys
    const int lane = tid & 63, wv = tid >> 6;
    const int ln15 = lane & 15, quad = lane >> 4;
    const int p2 = wv & 1;    // m-half: rows 32*p2..+32
    const int h2 = wv >> 1;   // QK: key-half; PV: n-half

    // Q A-fragments in registers (wave only needs its own 32 rows)
    bf16x8 qf[2][4];
    #pragma unroll
    for (int mt = 0; mt < 2; mt++)
        #pragma unroll
        for (int kk = 0; kk < 4; kk++) {
            int row = i0 + p2 * 32 + mt * 16 + ln15;
            qf[mt][kk] = *(const bf16x8*)(Qb + (size_t)row * 128 + kk * 32 + quad * 8);
        }
    const float kn2 = __uint_as_float(*knmax);
    float Msr[2][4];
    #pragma unroll
    for (int mt = 0; mt < 2; mt++)
        #pragma unroll
        for (int reg = 0; reg < 4; reg++) {
            int row = p2 * 32 + mt * 16 + quad * 4 + reg;
            Msr[mt][reg] = sqrtf(qn2[i0 + row] * kn2) * SCALE;
        }

    f32x4 acc[2][5];
    #pragma unroll
    for (int mt = 0; mt < 2; mt++)
        #pragma unroll
        for (int t = 0; t < 5; t++) acc[mt][t] = f32x4{0.f, 0.f, 0.f, 0.f};

    // prologue: issue Ks(0)
    #pragma unroll
    for (int i = 0; i < 4; i++) {
        int s = (i * 4 + wv) * 64 + lane;
        int r = s >> 4, g = (s & 15) ^ (r & 15);
        gl_lds16(Kb + (size_t)(k0 + r) * 128 + g * 8, &Ks[(i * 4 + wv) * 512]);
    }

    for (int c = 0; c < 32; c++) {
        const int kb = k0 + c * 64;
        // ---- barrier A: Ks(c) visible; PV(c-1) LDS reads done ----
        asm volatile("s_waitcnt vmcnt(0) lgkmcnt(0)" ::: "memory");
        __builtin_amdgcn_s_barrier();
        __builtin_amdgcn_sched_barrier(0);

        // Cs(c) DMA: 160 rows x 8 groups = 1280 slots, 5 wave-instrs
        // (safe: barrier A proved PV(c-1)'s Cs reads complete)
        #pragma unroll
        for (int i = 0; i < 5; i++) {
            int s = (i * 4 + wv) * 64 + lane;
            int r = s >> 3, g = (s & 7) ^ (r & 7);
            gl_lds16(CVbT + (size_t)r * 8192 + kb + g * 8, &Cs[(i * 4 + wv) * 512]);
        }
        __builtin_amdgcn_sched_barrier(0);   // pin DMA issue before QK

        // QK: rows 32*p2..+32 x keys 32*h2..+32
        f32x4 pacc[2][2];
        #pragma unroll
        for (int mt = 0; mt < 2; mt++)
            #pragma unroll
            for (int kt = 0; kt < 2; kt++) pacc[mt][kt] = f32x4{0.f, 0.f, 0.f, 0.f};
        #pragma unroll
        for (int kk = 0; kk < 4; kk++) {
            #pragma unroll
            for (int kt = 0; kt < 2; kt++) {
                int r = h2 * 32 + kt * 16 + ln15;
                int lg = kk * 4 + quad;
                bf16x8 bk = *(const bf16x8*)&Ks[r * 128 + ((lg ^ (r & 15)) * 8)];
                pacc[0][kt] = __builtin_amdgcn_mfma_f32_16x16x32_bf16(qf[0][kk], bk, pacc[0][kt], 0, 0, 0);
                pacc[1][kt] = __builtin_amdgcn_mfma_f32_16x16x32_bf16(qf[1][kk], bk, pacc[1][kt], 0, 0, 0);
            }
        }
        #pragma unroll
        for (int mt = 0; mt < 2; mt++)
            #pragma unroll
            for (int kt = 0; kt < 2; kt++)
                #pragma unroll
                for (int reg = 0; reg < 4; reg++) {
                    int row = p2 * 32 + mt * 16 + quad * 4 + reg;
                    int key = h2 * 32 + kt * 16 + ln15;
                    float p = __expf(pacc[mt][kt][reg] * SCALE - Msr[mt][reg]);
                    Ps[row][key] = f2bf(p);
                }

        // ---- barrier B: Cs(c) + Ps visible; Ks(c) reads done block-wide ----
        asm volatile("s_waitcnt vmcnt(0) lgkmcnt(0)" ::: "memory");
        __builtin_amdgcn_s_barrier();
        __builtin_amdgcn_sched_barrier(0);

        // Ks(c+1) DMA (safe: barrier B proved all QK reads of Ks done);
        // rides through the whole PV phase + next loop top.
        if (c + 1 < 32) {
            const int kb2 = k0 + (c + 1) * 64;
            #pragma unroll
            for (int i = 0; i < 4; i++) {
                int s = (i * 4 + wv) * 64 + lane;
                int r = s >> 4, g = (s & 15) ^ (r & 15);
                gl_lds16(Kb + (size_t)(kb2 + r) * 128 + g * 8, &Ks[(i * 4 + wv) * 512]);
            }
        }
        __builtin_amdgcn_sched_barrier(0);   // pin DMA issue before PV

        // PV: rows 32*p2..+32 x n = 80*h2..+80
        #pragma unroll
        for (int ks = 0; ks < 2; ks++) {
            bf16x4 lo0 = *(const bf16x4*)&Ps[p2 * 32 + ln15][ks * 32 + quad * 8];
            bf16x4 hi0 = *(const bf16x4*)&Ps[p2 * 32 + ln15][ks * 32 + quad * 8 + 4];
            bf16x4 lo1 = *(const bf16x4*)&Ps[p2 * 32 + 16 + ln15][ks * 32 + quad * 8];
            bf16x4 hi1 = *(const bf16x4*)&Ps[p2 * 32 + 16 + ln15][ks * 32 + quad * 8 + 4];
            bf16x8 ap0, ap1;
            #pragma unroll
            for (int j = 0; j < 4; j++) {
                ap0[j] = lo0[j]; ap0[j + 4] = hi0[j];
                ap1[j] = lo1[j]; ap1[j + 4] = hi1[j];
            }
            #pragma unroll
            for (int t = 0; t < 5; t++) {
                int n = h2 * 80 + t * 16 + ln15;
                int lg = ks * 4 + quad;
                bf16x8 bc = *(const bf16x8*)&Cs[n * 64 + ((lg ^ (n & 7)) * 8)];
                acc[0][t] = __builtin_amdgcn_mfma_f32_16x16x32_bf16(ap0, bc, acc[0][t], 0, 0, 0);
                acc[1][t] = __builtin_amdgcn_mfma_f32_16x16x32_bf16(ap1, bc, acc[1][t], 0, 0, 0);
            }
        }
    }
    // epilogue: plain stores into this split's disjoint partial buffer
    float* dst = Opart + (size_t)sp * 8192 * 160;
    #pragma unroll
    for (int mt = 0; mt < 2; mt++)
        #pragma unroll
        for (int t = 0; t < 5; t++)
            #pragma unroll
            for (int reg = 0; reg < 4; reg++) {
                int row = i0 + p2 * 32 + mt * 16 + quad * 4 + reg;
                int n = h2 * 80 + t * 16 + ln15;
                dst[(size_t)row * 160 + n] = acc[mt][t][reg];
            }
}

// ---------------------------------------------------------------------------
// Kernel 5: out = elu( (sum_sp O[sp]) / (sum_sp deno[sp] + 1e-9) ), 4 splits.
// ---------------------------------------------------------------------------
__global__ __launch_bounds__(256) void finalize_kernel(
    const float* __restrict__ Opart, float* __restrict__ out) {
    const size_t STR = (size_t)8192 * 160;
    int idx = blockIdx.x * 256 + threadIdx.x;
    int i = idx >> 7, n = idx & 127;
    const float* p = Opart + (size_t)i * 160;
    float val = 0.f, deno = 0.f;
    #pragma unroll
    for (int sp = 0; sp < 4; sp++) {
        val  += p[sp * STR + n];
        deno += p[sp * STR + 128];
    }
    float v = val / (deno + 1e-9f);
    out[idx] = (v > 0.f) ? v : expm1f(v);
}

// ---------------------------------------------------------------------------
extern "C" void kernel_launch(void* const* d_in, const int* in_sizes, int n_in,
                              void* d_out, int out_size, void* d_ws, size_t ws_size,
                              hipStream_t stream) {
    const float* feat = (const float*)d_in[0];
    // d_in[1] = bg (unused scalar)
    const float* C    = (const float*)d_in[2];
    const float* Wq   = (const float*)d_in[3];
    const float* Wk   = (const float*)d_in[4];
    const float* Wv   = (const float*)d_in[5];
    float* out = (float*)d_out;

    char* ws = (char*)d_ws;
    unsigned short* Qb    = (unsigned short*)(ws + 0);          // 2 MB
    unsigned short* Kb    = (unsigned short*)(ws + 2097152);    // 2 MB
    unsigned short* VbT   = (unsigned short*)(ws + 4194304);    // 192x8192x2 = 3 MB
    float*          CVpart= (float*)(ws + 7340032);             // 8x160x8192x4 = 40 MB
    unsigned short* CVbT  = (unsigned short*)(ws + 49283072);   // 160x8192x2 = 2.5 MB
    float*          Opart = (float*)(ws + 51904512);            // 4x8192x160x4 = 21 MB
    float*          qn2   = (float*)(ws + 93847552);            // 32 KB
    unsigned*       knmax = (unsigned*)(ws + 93880320);         // 4 B  (~90 MB total)

    hipMemsetAsync(knmax, 0, 4, stream);
    qkv_mfma<<<dim3(128, 3), 512, 0, stream>>>(feat, Wq, Wk, Wv, Qb, Kb, VbT);
    norms_kernel<<<256, 256, 0, stream>>>(Qb, Kb, qn2, knmax);
    cv_kernel<<<1024, 256, 0, stream>>>(C, VbT, CVpart);
    cvreduce_kernel<<<1280, 256, 0, stream>>>(CVpart, CVbT);
    flash_kernel<<<512, 256, 0, stream>>>(Qb, Kb, CVbT, qn2, knmax, Opart);
    finalize_kernel<<<4096, 256, 0, stream>>>(Opart, out);
}

// Round 5
// 486.829 us; speedup vs baseline: 1.0326x; 1.0035x over previous
//
#include <hip/hip_runtime.h>

// GKAT layer, restructured:
//   ret = elu( (S @ (C @ V_ext)) / (S @ rowsum(C) + eps) )
// where S = exp2(SC2*Q@K^T - M_i), M_i = ||Q_i|| * max_j ||K_j|| * SC2
// (Cauchy-Schwarz upper bound on rowmax; exact rowmax cancels in the ratio;
// SC2 = log2(e)/sqrt(128) so v_exp_f32 (2^x) is used directly).
// V_ext = [V | ones | pad] so rowsum(C) rides as column 128 of C@V_ext.
//
// R11 (instruction economy; R10 = 488.5us):
//  - norms fused into qkv epilogue (acc already holds full Q/K rows in fp32);
//    one atomicMax per K-block. norms_kernel dispatch deleted.
//  - v_cvt_pk_bf16_f32 replaces 4-op manual RNE f2bf in pack8 (qkv/cv
//    staging), flash P-convert, qkv V-epilogue, cvreduce.
//  - v_exp_f32 (2^x) direct with log2e folded into scale and Msr.

typedef __attribute__((ext_vector_type(8))) short bf16x8;   // 8 bf16 (4 VGPRs)
typedef __attribute__((ext_vector_type(4))) short bf16x4;   // 8-byte LDS loads
typedef __attribute__((ext_vector_type(4))) float f32x4;

// SC2 = (1/sqrt(128)) * log2(e)
#define SC2 (0.088388347648318447f * 1.4426950408889634f)

static __device__ __forceinline__ unsigned short f2bf(float f) {
    unsigned u = __float_as_uint(f);
    u = (u + 0x7fffu + ((u >> 16) & 1u)) >> 16;   // RNE
    return (unsigned short)u;
}
static __device__ __forceinline__ float bf2f(unsigned short b) {
    return __uint_as_float(((unsigned)b) << 16);
}
// packed f32x2 -> bf16x2 (RNE), single HW instr
static __device__ __forceinline__ unsigned pkbf(float lo, float hi) {
    unsigned r;
    asm("v_cvt_pk_bf16_f32 %0, %1, %2" : "=v"(r) : "v"(lo), "v"(hi));
    return r;
}
static __device__ __forceinline__ float fexp2(float x) {   // 2^x
    float r;
    asm("v_exp_f32 %0, %1" : "=v"(r) : "v"(x));
    return r;
}
static __device__ __forceinline__ bf16x8 pack8(const float4& a, const float4& b) {
    union { unsigned u[4]; bf16x8 v; } o;
    o.u[0] = pkbf(a.x, a.y); o.u[1] = pkbf(a.z, a.w);
    o.u[2] = pkbf(b.x, b.y); o.u[3] = pkbf(b.z, b.w);
    return o.v;
}
// async global->LDS DMA, 16B/lane; LDS dest = wave-uniform base + lane*16
static __device__ __forceinline__ void gl_lds16(const unsigned short* g, unsigned short* l) {
    __builtin_amdgcn_global_load_lds(
        (const __attribute__((address_space(1))) unsigned int*)g,
        (__attribute__((address_space(3))) unsigned int*)l, 16, 0, 0);
}

// ---------------------------------------------------------------------------
// Kernel 1: one block = 64 feat rows x one full W matrix.
// R11: row norms fused into the epilogue (Q: qn2 store; K: block atomicMax).
// ---------------------------------------------------------------------------
__global__ __launch_bounds__(512) void qkv_mfma(
    const float* __restrict__ feat, const float* __restrict__ Wq,
    const float* __restrict__ Wk, const float* __restrict__ Wv,
    unsigned short* __restrict__ Qb, unsigned short* __restrict__ Kb,
    unsigned short* __restrict__ VbT, float* __restrict__ qn2,
    unsigned* __restrict__ knmax) {
    __shared__ unsigned short As[64][264];
    __shared__ unsigned short Bs[128][264];
    __shared__ float sn[2][64];
    const int tid = threadIdx.x;
    const int m0 = blockIdx.x * 64;
    const int mat = blockIdx.y;
    const float* W = (mat == 0) ? Wq : (mat == 1) ? Wk : Wv;
    const int lane = tid & 63, wv = tid >> 6;
    const int wm = wv & 3, wn = wv >> 2;
    const int ln15 = lane & 15, quad = lane >> 4;

    #pragma unroll
    for (int i = 0; i < 4; i++) {
        int s = tid + i * 512;
        int r = s >> 5, c8 = s & 31;
        const float* p = feat + (size_t)(m0 + r) * 256 + c8 * 8;
        const float4 f0 = *(const float4*)p;
        const float4 f1 = *(const float4*)(p + 4);
        *(bf16x8*)&As[r][c8 * 8] = pack8(f0, f1);
    }
    #pragma unroll
    for (int i = 0; i < 16; i++) {
        int s = tid + i * 512;
        int k = s >> 5, n4 = (s & 31) * 4;
        const float4 f = *(const float4*)(W + (size_t)k * 128 + n4);
        Bs[n4 + 0][k] = f2bf(f.x); Bs[n4 + 1][k] = f2bf(f.y);
        Bs[n4 + 2][k] = f2bf(f.z); Bs[n4 + 3][k] = f2bf(f.w);
    }
    __syncthreads();

    f32x4 acc[4];
    #pragma unroll
    for (int t = 0; t < 4; t++) acc[t] = f32x4{0.f, 0.f, 0.f, 0.f};
    #pragma unroll
    for (int ks = 0; ks < 8; ks++) {
        bf16x8 af = *(const bf16x8*)&As[wm * 16 + ln15][ks * 32 + quad * 8];
        #pragma unroll
        for (int t = 0; t < 4; t++) {
            bf16x8 bf = *(const bf16x8*)&Bs[wn * 64 + t * 16 + ln15][ks * 32 + quad * 8];
            acc[t] = __builtin_amdgcn_mfma_f32_16x16x32_bf16(af, bf, acc[t], 0, 0, 0);
        }
    }
    #pragma unroll
    for (int t = 0; t < 4; t++) {
        int n = wn * 64 + t * 16 + ln15;
        int mb = m0 + wm * 16 + quad * 4;
        if (mat == 2) {
            uint2 w;
            w.x = pkbf(acc[t][0], acc[t][1]);
            w.y = pkbf(acc[t][2], acc[t][3]);
            *(uint2*)(VbT + (size_t)n * 8192 + mb) = w;
        } else {
            unsigned short* dst = (mat == 0) ? Qb : Kb;
            #pragma unroll
            for (int reg = 0; reg < 4; reg++)
                dst[(size_t)(mb + reg) * 128 + n] = f2bf(acc[t][reg]);
        }
    }
    if (mat == 2) {
        #pragma unroll
        for (int i = 0; i < 8; i++) {
            int idx = tid + i * 512;
            int rr = idx >> 6, c = idx & 63;
            VbT[(size_t)(128 + rr) * 8192 + m0 + c] =
                (rr == 0) ? (unsigned short)0x3F80 : (unsigned short)0;
        }
    } else {
        // fused row norms: rows wm*16+quad*4+reg; cols spread over ln15 x t x wn
        float s[4];
        #pragma unroll
        for (int reg = 0; reg < 4; reg++) {
            float x = acc[0][reg] * acc[0][reg] + acc[1][reg] * acc[1][reg]
                    + acc[2][reg] * acc[2][reg] + acc[3][reg] * acc[3][reg];
            #pragma unroll
            for (int m = 1; m < 16; m <<= 1) x += __shfl_xor(x, m, 64);
            s[reg] = x;
        }
        if (ln15 == 0) {
            #pragma unroll
            for (int reg = 0; reg < 4; reg++)
                sn[wn][wm * 16 + quad * 4 + reg] = s[reg];
        }
        __syncthreads();
        if (tid < 64) {
            float tot = sn[0][tid] + sn[1][tid];
            if (mat == 0) {
                qn2[m0 + tid] = tot;
            } else {
                #pragma unroll
                for (int m = 1; m < 64; m <<= 1)
                    tot = fmaxf(tot, __shfl_xor(tot, m, 64));
                if (tid == 0) atomicMax(knmax, __float_as_uint(tot));
            }
        }
    }
}

// ---------------------------------------------------------------------------
// Kernel 3: CVpart[sp] = C[m-range][k-range] @ V_ext^T.  M=64/block,
// ksplit 8 -> grid 1024 (4 blocks/CU, balanced).  A read fp32 directly
// (dist-1 reg prefetch), B via 16B DMA.  XOR-swizzled.  Counted vmcnt(4).
// ---------------------------------------------------------------------------
__global__ __launch_bounds__(256, 4) void cv_kernel(
    const float* __restrict__ C, const unsigned short* __restrict__ VbT,
    float* __restrict__ CVpart) {
    __shared__ unsigned short As[64 * 64];    // 8 KB, swizzled
    __shared__ unsigned short Bs[192 * 64];   // 24 KB, swizzled
    const int tid = threadIdx.x;
    const int rg = blockIdx.x >> 3, sp = blockIdx.x & 7;
    const int m0 = rg * 64;
    const int k0 = sp * 1024;                 // 16 chunks of 64
    const int lane = tid & 63, wv = tid >> 6;
    const int mh = wv & 1, h2 = wv >> 1;
    const int ln15 = lane & 15, quad = lane >> 4;

    const int r0 = tid >> 3, gc = tid & 7;    // A slots: (r0, gc) and (r0+32, gc)
    const int gsw = gc ^ (r0 & 7);            // (r0+32)&7 == r0&7
    const float* A0 = C + (size_t)(m0 + r0) * 8192 + k0 + gc * 8;
    const float* A1 = A0 + (size_t)32 * 8192;

    float4 pa[4];
    pa[0] = *(const float4*)A0; pa[1] = *(const float4*)(A0 + 4);
    pa[2] = *(const float4*)A1; pa[3] = *(const float4*)(A1 + 4);

    f32x4 acc[2][5];
    #pragma unroll
    for (int mt = 0; mt < 2; mt++)
        #pragma unroll
        for (int t = 0; t < 5; t++) acc[mt][t] = f32x4{0.f, 0.f, 0.f, 0.f};

    const int ra0 = mh * 32 + ln15;
    const int ra1 = mh * 32 + 16 + ln15;

    for (int c = 0; c < 16; c++) {
        __syncthreads();   // prev chunk's LDS reads done; prefetch regs drained
        *(bf16x8*)&As[r0 * 64 + gsw * 8]        = pack8(pa[0], pa[1]);
        *(bf16x8*)&As[(r0 + 32) * 64 + gsw * 8] = pack8(pa[2], pa[3]);
        // B DMA: 192 rows x 8 groups = 1536 slots, 6 wave-instrs
        #pragma unroll
        for (int i = 0; i < 6; i++) {
            int s = (i * 4 + wv) * 64 + lane;
            int r = s >> 3, g = (s & 7) ^ (r & 7);
            gl_lds16(VbT + (size_t)r * 8192 + k0 + c * 64 + g * 8,
                     &Bs[(i * 4 + wv) * 512]);
        }
        // compiler memory fence: prefetch loads must ISSUE after the 6 DMAs
        // so the counted vmcnt below refers to the DMAs.
        asm volatile("" ::: "memory");
        if (c + 1 < 16) {   // dist-1 prefetch of next A chunk (fp32)
            const float* p0 = A0 + (c + 1) * 64;
            const float* p1 = A1 + (c + 1) * 64;
            pa[0] = *(const float4*)p0; pa[1] = *(const float4*)(p0 + 4);
            pa[2] = *(const float4*)p1; pa[3] = *(const float4*)(p1 + 4);
            // 6 DMA + 4 prefetch outstanding; wait DMAs only (oldest 6)
            asm volatile("s_waitcnt vmcnt(4) lgkmcnt(0)" ::: "memory");
        } else {
            asm volatile("s_waitcnt vmcnt(0) lgkmcnt(0)" ::: "memory");
        }
        __builtin_amdgcn_s_barrier();
        __builtin_amdgcn_sched_barrier(0);
        #pragma unroll
        for (int k2 = 0; k2 < 2; k2++) {
            const int lg = k2 * 4 + quad;
            bf16x8 a0 = *(const bf16x8*)&As[ra0 * 64 + ((lg ^ (ra0 & 7)) * 8)];
            bf16x8 a1 = *(const bf16x8*)&As[ra1 * 64 + ((lg ^ (ra1 & 7)) * 8)];
            #pragma unroll
            for (int t = 0; t < 5; t++) {
                int n = h2 * 80 + t * 16 + ln15;
                bf16x8 bf = *(const bf16x8*)&Bs[n * 64 + ((lg ^ (n & 7)) * 8)];
                acc[0][t] = __builtin_amdgcn_mfma_f32_16x16x32_bf16(a0, bf, acc[0][t], 0, 0, 0);
                acc[1][t] = __builtin_amdgcn_mfma_f32_16x16x32_bf16(a1, bf, acc[1][t], 0, 0, 0);
            }
        }
    }
    float* dst = CVpart + (size_t)sp * 160 * 8192;
    #pragma unroll
    for (int mt = 0; mt < 2; mt++)
        #pragma unroll
        for (int t = 0; t < 5; t++) {
            int n = h2 * 80 + t * 16 + ln15;
            int m = m0 + mh * 32 + mt * 16 + quad * 4;
            float4 w;
            w.x = acc[mt][t][0]; w.y = acc[mt][t][1];
            w.z = acc[mt][t][2]; w.w = acc[mt][t][3];
            *(float4*)(dst + (size_t)n * 8192 + m) = w;
        }
}

// ---------------------------------------------------------------------------
// Kernel 3b: CVbT bf16 = sum of 8 partials.
// ---------------------------------------------------------------------------
__global__ __launch_bounds__(256) void cvreduce_kernel(
    const float* __restrict__ CVpart, unsigned short* __restrict__ CVbT) {
    const size_t STR = (size_t)160 * 8192;
    int idx = blockIdx.x * 256 + threadIdx.x;    // 327680 float4-slots
    const float* p = CVpart + (size_t)idx * 4;
    float4 s = *(const float4*)p;
    #pragma unroll
    for (int j = 1; j < 8; j++) {
        const float4 q = *(const float4*)(p + j * STR);
        s.x += q.x; s.y += q.y; s.z += q.z; s.w += q.w;
    }
    uint2 w;
    w.x = pkbf(s.x, s.y); w.y = pkbf(s.z, s.w);
    *(uint2*)(CVbT + (size_t)idx * 4) = w;
}

// ---------------------------------------------------------------------------
// Kernel 4: ksplit 4, M=64 -> grid 512 = exactly 2 blocks/CU, balanced.
// 32 chunks/block. 2-barrier pipelined loop:
//   barrier A (Ks(c) ready) -> issue Cs(c) -> QK+exp ->
//   barrier B (Cs+Ps ready) -> issue Ks(c+1) -> PV
// ---------------------------------------------------------------------------
__global__ __launch_bounds__(256, 2) void flash_kernel(
    const unsigned short* __restrict__ Qb, const unsigned short* __restrict__ Kb,
    const unsigned short* __restrict__ CVbT, const float* __restrict__ qn2,
    const unsigned* __restrict__ knmax, float* __restrict__ Opart) {
    __shared__ unsigned short Ks[64 * 128];   // 16 KB, 16-group swizzle
    __shared__ unsigned short Cs[160 * 64];   // 20 KB, 8-group swizzle
    __shared__ unsigned short Ps[64][68];     // 8.5 KB
    const int tid = threadIdx.x;
    const int rg = blockIdx.x >> 2, sp = blockIdx.x & 3;
    const int i0 = rg * 64;
    const int k0 = sp * 2048;                 // 32 chunks of 64 keys
    const int lane = tid & 63, wv = tid >> 6;
    const int ln15 = lane & 15, quad = lane >> 4;
    const int p2 = wv & 1;    // m-half: rows 32*p2..+32
    const int h2 = wv >> 1;   // QK: key-half; PV: n-half

    // Q A-fragments in registers (wave only needs its own 32 rows)
    bf16x8 qf[2][4];
    #pragma unroll
    for (int mt = 0; mt < 2; mt++)
        #pragma unroll
        for (int kk = 0; kk < 4; kk++) {
            int row = i0 + p2 * 32 + mt * 16 + ln15;
            qf[mt][kk] = *(const bf16x8*)(Qb + (size_t)row * 128 + kk * 32 + quad * 8);
        }
    const float kn2 = __uint_as_float(*knmax);
    float Msr[2][4];
    #pragma unroll
    for (int mt = 0; mt < 2; mt++)
        #pragma unroll
        for (int reg = 0; reg < 4; reg++) {
            int row = p2 * 32 + mt * 16 + quad * 4 + reg;
            Msr[mt][reg] = sqrtf(qn2[i0 + row] * kn2) * SC2;
        }

    f32x4 acc[2][5];
    #pragma unroll
    for (int mt = 0; mt < 2; mt++)
        #pragma unroll
        for (int t = 0; t < 5; t++) acc[mt][t] = f32x4{0.f, 0.f, 0.f, 0.f};

    // prologue: issue Ks(0)
    #pragma unroll
    for (int i = 0; i < 4; i++) {
        int s = (i * 4 + wv) * 64 + lane;
        int r = s >> 4, g = (s & 15) ^ (r & 15);
        gl_lds16(Kb + (size_t)(k0 + r) * 128 + g * 8, &Ks[(i * 4 + wv) * 512]);
    }

    for (int c = 0; c < 32; c++) {
        const int kb = k0 + c * 64;
        // ---- barrier A: Ks(c) visible; PV(c-1) LDS reads done ----
        asm volatile("s_waitcnt vmcnt(0) lgkmcnt(0)" ::: "memory");
        __builtin_amdgcn_s_barrier();
        __builtin_amdgcn_sched_barrier(0);

        // Cs(c) DMA: 160 rows x 8 groups = 1280 slots, 5 wave-instrs
        // (safe: barrier A proved PV(c-1)'s Cs reads complete)
        #pragma unroll
        for (int i = 0; i < 5; i++) {
            int s = (i * 4 + wv) * 64 + lane;
            int r = s >> 3, g = (s & 7) ^ (r & 7);
            gl_lds16(CVbT + (size_t)r * 8192 + kb + g * 8, &Cs[(i * 4 + wv) * 512]);
        }
        __builtin_amdgcn_sched_barrier(0);   // pin DMA issue before QK

        // QK: rows 32*p2..+32 x keys 32*h2..+32
        f32x4 pacc[2][2];
        #pragma unroll
        for (int mt = 0; mt < 2; mt++)
            #pragma unroll
            for (int kt = 0; kt < 2; kt++) pacc[mt][kt] = f32x4{0.f, 0.f, 0.f, 0.f};
        #pragma unroll
        for (int kk = 0; kk < 4; kk++) {
            #pragma unroll
            for (int kt = 0; kt < 2; kt++) {
                int r = h2 * 32 + kt * 16 + ln15;
                int lg = kk * 4 + quad;
                bf16x8 bk = *(const bf16x8*)&Ks[r * 128 + ((lg ^ (r & 15)) * 8)];
                pacc[0][kt] = __builtin_amdgcn_mfma_f32_16x16x32_bf16(qf[0][kk], bk, pacc[0][kt], 0, 0, 0);
                pacc[1][kt] = __builtin_amdgcn_mfma_f32_16x16x32_bf16(qf[1][kk], bk, pacc[1][kt], 0, 0, 0);
            }
        }
        #pragma unroll
        for (int mt = 0; mt < 2; mt++)
            #pragma unroll
            for (int kt = 0; kt < 2; kt++) {
                int key = h2 * 32 + kt * 16 + ln15;
                int row0 = p2 * 32 + mt * 16 + quad * 4;
                float e0 = fexp2(pacc[mt][kt][0] * SC2 - Msr[mt][0]);
                float e1 = fexp2(pacc[mt][kt][1] * SC2 - Msr[mt][1]);
                float e2 = fexp2(pacc[mt][kt][2] * SC2 - Msr[mt][2]);
                float e3 = fexp2(pacc[mt][kt][3] * SC2 - Msr[mt][3]);
                unsigned p01 = pkbf(e0, e1), p23 = pkbf(e2, e3);
                Ps[row0 + 0][key] = (unsigned short)(p01 & 0xffffu);
                Ps[row0 + 1][key] = (unsigned short)(p01 >> 16);
                Ps[row0 + 2][key] = (unsigned short)(p23 & 0xffffu);
                Ps[row0 + 3][key] = (unsigned short)(p23 >> 16);
            }

        // ---- barrier B: Cs(c) + Ps visible; Ks(c) reads done block-wide ----
        asm volatile("s_waitcnt vmcnt(0) lgkmcnt(0)" ::: "memory");
        __builtin_amdgcn_s_barrier();
        __builtin_amdgcn_sched_barrier(0);

        // Ks(c+1) DMA (safe: barrier B proved all QK reads of Ks done);
        // rides through the whole PV phase + next loop top.
        if (c + 1 < 32) {
            const int kb2 = k0 + (c + 1) * 64;
            #pragma unroll
            for (int i = 0; i < 4; i++) {
                int s = (i * 4 + wv) * 64 + lane;
                int r = s >> 4, g = (s & 15) ^ (r & 15);
                gl_lds16(Kb + (size_t)(kb2 + r) * 128 + g * 8, &Ks[(i * 4 + wv) * 512]);
            }
        }
        __builtin_amdgcn_sched_barrier(0);   // pin DMA issue before PV

        // PV: rows 32*p2..+32 x n = 80*h2..+80
        #pragma unroll
        for (int ks = 0; ks < 2; ks++) {
            bf16x4 lo0 = *(const bf16x4*)&Ps[p2 * 32 + ln15][ks * 32 + quad * 8];
            bf16x4 hi0 = *(const bf16x4*)&Ps[p2 * 32 + ln15][ks * 32 + quad * 8 + 4];
            bf16x4 lo1 = *(const bf16x4*)&Ps[p2 * 32 + 16 + ln15][ks * 32 + quad * 8];
            bf16x4 hi1 = *(const bf16x4*)&Ps[p2 * 32 + 16 + ln15][ks * 32 + quad * 8 + 4];
            bf16x8 ap0, ap1;
            #pragma unroll
            for (int j = 0; j < 4; j++) {
                ap0[j] = lo0[j]; ap0[j + 4] = hi0[j];
                ap1[j] = lo1[j]; ap1[j + 4] = hi1[j];
            }
            #pragma unroll
            for (int t = 0; t < 5; t++) {
                int n = h2 * 80 + t * 16 + ln15;
                int lg = ks * 4 + quad;
                bf16x8 bc = *(const bf16x8*)&Cs[n * 64 + ((lg ^ (n & 7)) * 8)];
                acc[0][t] = __builtin_amdgcn_mfma_f32_16x16x32_bf16(ap0, bc, acc[0][t], 0, 0, 0);
                acc[1][t] = __builtin_amdgcn_mfma_f32_16x16x32_bf16(ap1, bc, acc[1][t], 0, 0, 0);
            }
        }
    }
    // epilogue: plain stores into this split's disjoint partial buffer
    float* dst = Opart + (size_t)sp * 8192 * 160;
    #pragma unroll
    for (int mt = 0; mt < 2; mt++)
        #pragma unroll
        for (int t = 0; t < 5; t++)
            #pragma unroll
            for (int reg = 0; reg < 4; reg++) {
                int row = i0 + p2 * 32 + mt * 16 + quad * 4 + reg;
                int n = h2 * 80 + t * 16 + ln15;
                dst[(size_t)row * 160 + n] = acc[mt][t][reg];
            }
}

// ---------------------------------------------------------------------------
// Kernel 5: out = elu( (sum_sp O[sp]) / (sum_sp deno[sp] + 1e-9) ), 4 splits.
// ---------------------------------------------------------------------------
__global__ __launch_bounds__(256) void finalize_kernel(
    const float* __restrict__ Opart, float* __restrict__ out) {
    const size_t STR = (size_t)8192 * 160;
    int idx = blockIdx.x * 256 + threadIdx.x;
    int i = idx >> 7, n = idx & 127;
    const float* p = Opart + (size_t)i * 160;
    float val = 0.f, deno = 0.f;
    #pragma unroll
    for (int sp = 0; sp < 4; sp++) {
        val  += p[sp * STR + n];
        deno += p[sp * STR + 128];
    }
    float v = val / (deno + 1e-9f);
    out[idx] = (v > 0.f) ? v : expm1f(v);
}

// ---------------------------------------------------------------------------
extern "C" void kernel_launch(void* const* d_in, const int* in_sizes, int n_in,
                              void* d_out, int out_size, void* d_ws, size_t ws_size,
                              hipStream_t stream) {
    const float* feat = (const float*)d_in[0];
    // d_in[1] = bg (unused scalar)
    const float* C    = (const float*)d_in[2];
    const float* Wq   = (const float*)d_in[3];
    const float* Wk   = (const float*)d_in[4];
    const float* Wv   = (const float*)d_in[5];
    float* out = (float*)d_out;

    char* ws = (char*)d_ws;
    unsigned short* Qb    = (unsigned short*)(ws + 0);          // 2 MB
    unsigned short* Kb    = (unsigned short*)(ws + 2097152);    // 2 MB
    unsigned short* VbT   = (unsigned short*)(ws + 4194304);    // 192x8192x2 = 3 MB
    float*          CVpart= (float*)(ws + 7340032);             // 8x160x8192x4 = 40 MB
    unsigned short* CVbT  = (unsigned short*)(ws + 49283072);   // 160x8192x2 = 2.5 MB
    float*          Opart = (float*)(ws + 51904512);            // 4x8192x160x4 = 21 MB
    float*          qn2   = (float*)(ws + 93847552);            // 32 KB
    unsigned*       knmax = (unsigned*)(ws + 93880320);         // 4 B  (~90 MB total)

    hipMemsetAsync(knmax, 0, 4, stream);
    qkv_mfma<<<dim3(128, 3), 512, 0, stream>>>(feat, Wq, Wk, Wv, Qb, Kb, VbT, qn2, knmax);
    cv_kernel<<<1024, 256, 0, stream>>>(C, VbT, CVpart);
    cvreduce_kernel<<<1280, 256, 0, stream>>>(CVpart, CVbT);
    flash_kernel<<<512, 256, 0, stream>>>(Qb, Kb, CVbT, qn2, knmax, Opart);
    finalize_kernel<<<4096, 256, 0, stream>>>(Opart, out);
}